// Round 4
// baseline (396.926 us; speedup 1.0000x reference)
//
#include <hip/hip_runtime.h>

#define S_LEN 256
#define B_SZ  512
#define T_TAGS 128
#define TP2   130
#define PAD_I (-1)

#define ROWS_PB    16
#define FWD_BLOCKS (B_SZ / ROWS_PB)   // 32
#define NQ         32
#define QLEN       (S_LEN / NQ)       // 8
#define NUM_BLOCKS 64                 // numerator: 2 blocks per s-chunk
#define TOT_BLOCKS (FWD_BLOCKS + NUM_BLOCKS)

typedef __bf16 bf16x8 __attribute__((ext_vector_type(8)));
typedef float  f32x4  __attribute__((ext_vector_type(4)));

// LDS-only barrier: drains LDS ops, leaves global loads in flight.
__device__ __forceinline__ void bar_lds() {
    asm volatile("s_waitcnt lgkmcnt(0)\n\ts_barrier" ::: "memory");
}

// fwd: one block = 16 batch rows. 4 waves; wave w owns dest-tag cols [32w,32w+32).
// State lp lives in MFMA C-layout: lane l: batch m=(l>>4)*4+r, col n=32w+16nt+(l&15).
// Per step: A = P (16 batches x 128 src-tags, bf16) from LDS transpose;
// B = exp(trans_tt) held in registers forever.
__global__ __launch_bounds__(256) void crf_main(
    const float* __restrict__ em,     // (S,B,T)
    const float* __restrict__ trans,  // (T+2,T+2)
    const int*   __restrict__ tags,   // (S,B)
    float* __restrict__ denom_out,    // (B)
    float* __restrict__ pl,           // (NQ,B)
    int*   __restrict__ pc)           // (NQ,B)
{
    if (blockIdx.x < FWD_BLOCKS) {
        const int t  = threadIdx.x;
        const int l  = t & 63;
        const int w  = t >> 6;        // wave 0..3
        const int lm = l & 15;
        const int lg = l >> 4;        // 0..3
        const int m0 = lg * 4;        // batch group for C-layout
        const int b0 = blockIdx.x * ROWS_PB;
        const int wb = w * 32;

        __shared__ float P_lds[2][T_TAGS][16];   // [k][m] col-major f32, double buffered
        __shared__ float wmax[2][16][4];         // [m][wave] partial row-max
        __shared__ float smA[16][4];
        __shared__ float smB[16][4];

        // B fragments: E[k][n], lane: n = wb+16nt+lm, k-run = ks*32 + lg*8 + e
        bf16x8 bf[2][4];
        #pragma unroll
        for (int nt = 0; nt < 2; ++nt)
            #pragma unroll
            for (int ks = 0; ks < 4; ++ks)
                #pragma unroll
                for (int e = 0; e < 8; ++e)
                    bf[nt][ks][e] = (__bf16)__expf(trans[(ks*32 + lg*8 + e)*TP2 + (wb + nt*16 + lm)]);
        const float te0 = trans[(wb + lm)*TP2 + (T_TAGS + 1)];
        const float te1 = trans[(wb + 16 + lm)*TP2 + (T_TAGS + 1)];

        // initial state lp0 = trans[start][n] + em[0][b][n]
        float lp[2][4];
        #pragma unroll
        for (int nt = 0; nt < 2; ++nt)
            #pragma unroll
            for (int r = 0; r < 4; ++r)
                lp[nt][r] = trans[T_TAGS*TP2 + (wb + nt*16 + lm)]
                          + em[(size_t)(b0 + m0 + r)*T_TAGS + (wb + nt*16 + lm)];

        // P_1 = exp(lp0) (scale M=0, safe: lp0 <= ~6), slot 1
        #pragma unroll
        for (int nt = 0; nt < 2; ++nt) {
            f32x4 pv;
            #pragma unroll
            for (int r = 0; r < 4; ++r) pv[r] = __expf(lp[nt][r]);
            *(f32x4*)&P_lds[1][wb + nt*16 + lm][m0] = pv;
        }
        // wave-partial row-max of lp0 -> wmax slot 0
        {
            float rm[4];
            #pragma unroll
            for (int r = 0; r < 4; ++r) rm[r] = fmaxf(lp[0][r], lp[1][r]);
            #pragma unroll
            for (int st = 1; st < 16; st <<= 1)
                #pragma unroll
                for (int r = 0; r < 4; ++r) rm[r] = fmaxf(rm[r], __shfl_xor(rm[r], st));
            if (lm < 4) {
                float v = (lm == 0) ? rm[0] : (lm == 1) ? rm[1] : (lm == 2) ? rm[2] : rm[3];
                wmax[0][m0 + lm][w] = v;
            }
        }
        // prefetch step-1 emissions/tags
        float ec[2][4]; int tgc[4];
        #pragma unroll
        for (int nt = 0; nt < 2; ++nt)
            #pragma unroll
            for (int r = 0; r < 4; ++r)
                ec[nt][r] = em[((size_t)1*B_SZ + b0 + m0 + r)*T_TAGS + (wb + nt*16 + lm)];
        #pragma unroll
        for (int r = 0; r < 4; ++r) tgc[r] = tags[1*B_SZ + b0 + m0 + r];

        float Mc[4] = {0.f, 0.f, 0.f, 0.f};   // scale used in P for current step
        bar_lds();

        for (int s = 1; s < S_LEN; ++s) {
            const int rb = s & 1;
            // A fragments: lane: batch m=lm, k = ks*32 + lg*8 + e  (2-way bank alias = free)
            const float* pb = &P_lds[rb][lg*8][lm];
            bf16x8 af[4];
            #pragma unroll
            for (int ks = 0; ks < 4; ++ks)
                #pragma unroll
                for (int e = 0; e < 8; ++e)
                    af[ks][e] = (__bf16)pb[(ks*32 + e)*16];
            // combine stale row-max (written last step) -> scale for P_{s+1}
            float Mn[4];
            #pragma unroll
            for (int r = 0; r < 4; ++r) {
                f32x4 wv = *(const f32x4*)&wmax[(s - 1) & 1][m0 + r][0];
                Mn[r] = fmaxf(fmaxf(wv[0], wv[1]), fmaxf(wv[2], wv[3]));
            }
            // prefetch next emissions/tags (latency hides under MFMA+update)
            float en[2][4]; int tgn[4];
            if (s < S_LEN - 1) {
                #pragma unroll
                for (int nt = 0; nt < 2; ++nt)
                    #pragma unroll
                    for (int r = 0; r < 4; ++r)
                        en[nt][r] = em[((size_t)(s + 1)*B_SZ + b0 + m0 + r)*T_TAGS + (wb + nt*16 + lm)];
                #pragma unroll
                for (int r = 0; r < 4; ++r) tgn[r] = tags[(s + 1)*B_SZ + b0 + m0 + r];
            }
            // D = P x E  (fresh accumulate per step)
            f32x4 d0, d1;
            {
                const f32x4 z = {0.f, 0.f, 0.f, 0.f};
                d0 = __builtin_amdgcn_mfma_f32_16x16x32_bf16(af[0], bf[0][0], z, 0, 0, 0);
                d1 = __builtin_amdgcn_mfma_f32_16x16x32_bf16(af[0], bf[1][0], z, 0, 0, 0);
                #pragma unroll
                for (int ks = 1; ks < 4; ++ks) {
                    d0 = __builtin_amdgcn_mfma_f32_16x16x32_bf16(af[ks], bf[0][ks], d0, 0, 0, 0);
                    d1 = __builtin_amdgcn_mfma_f32_16x16x32_bf16(af[ks], bf[1][ks], d1, 0, 0, 0);
                }
            }
            // state update: nlp = Mc + log(d) + e ; keep old on PAD
            #pragma unroll
            for (int r = 0; r < 4; ++r) {
                const float nl0 = Mc[r] + __logf(d0[r]) + ec[0][r];
                const float nl1 = Mc[r] + __logf(d1[r]) + ec[1][r];
                lp[0][r] = (tgc[r] != PAD_I) ? nl0 : lp[0][r];
                lp[1][r] = (tgc[r] != PAD_I) ? nl1 : lp[1][r];
            }
            // write P_{s+1} = exp(lp - Mn) into slot rb^1 (b128, conflict-free)
            #pragma unroll
            for (int nt = 0; nt < 2; ++nt) {
                f32x4 pv;
                #pragma unroll
                for (int r = 0; r < 4; ++r) pv[r] = __expf(lp[nt][r] - Mn[r]);
                *(f32x4*)&P_lds[rb ^ 1][wb + nt*16 + lm][m0] = pv;
            }
            // wave-partial row-max of new lp -> wmax slot s&1
            {
                float rm[4];
                #pragma unroll
                for (int r = 0; r < 4; ++r) rm[r] = fmaxf(lp[0][r], lp[1][r]);
                #pragma unroll
                for (int st = 1; st < 16; st <<= 1)
                    #pragma unroll
                    for (int r = 0; r < 4; ++r) rm[r] = fmaxf(rm[r], __shfl_xor(rm[r], st));
                if (lm < 4) {
                    float v = (lm == 0) ? rm[0] : (lm == 1) ? rm[1] : (lm == 2) ? rm[2] : rm[3];
                    wmax[s & 1][m0 + lm][w] = v;
                }
            }
            #pragma unroll
            for (int r = 0; r < 4; ++r) Mc[r] = Mn[r];
            if (s < S_LEN - 1) {
                #pragma unroll
                for (int nt = 0; nt < 2; ++nt)
                    #pragma unroll
                    for (int r = 0; r < 4; ++r) ec[nt][r] = en[nt][r];
                #pragma unroll
                for (int r = 0; r < 4; ++r) tgc[r] = tgn[r];
            }
            bar_lds();
        }

        // epilogue: denom[b] = logsumexp_j(lp + trans[j][end])
        float v0[4], v1[4], rm[4];
        #pragma unroll
        for (int r = 0; r < 4; ++r) {
            v0[r] = lp[0][r] + te0;
            v1[r] = lp[1][r] + te1;
            rm[r] = fmaxf(v0[r], v1[r]);
        }
        #pragma unroll
        for (int st = 1; st < 16; st <<= 1)
            #pragma unroll
            for (int r = 0; r < 4; ++r) rm[r] = fmaxf(rm[r], __shfl_xor(rm[r], st));
        if (lm < 4) {
            float v = (lm == 0) ? rm[0] : (lm == 1) ? rm[1] : (lm == 2) ? rm[2] : rm[3];
            smA[m0 + lm][w] = v;
        }
        bar_lds();
        float sm[4];
        #pragma unroll
        for (int r = 0; r < 4; ++r) {
            f32x4 a4 = *(const f32x4*)&smA[m0 + r][0];
            const float M = fmaxf(fmaxf(a4[0], a4[1]), fmaxf(a4[2], a4[3]));
            sm[r] = __expf(v0[r] - M) + __expf(v1[r] - M);
        }
        #pragma unroll
        for (int st = 1; st < 16; st <<= 1)
            #pragma unroll
            for (int r = 0; r < 4; ++r) sm[r] += __shfl_xor(sm[r], st);
        if (lm < 4) {
            float v = (lm == 0) ? sm[0] : (lm == 1) ? sm[1] : (lm == 2) ? sm[2] : sm[3];
            smB[m0 + lm][w] = v;
        }
        bar_lds();
        if (t < 16) {
            f32x4 a4 = *(const f32x4*)&smA[t][0];
            const float M = fmaxf(fmaxf(a4[0], a4[1]), fmaxf(a4[2], a4[3]));
            f32x4 s4 = *(const f32x4*)&smB[t][0];
            denom_out[b0 + t] = M + __logf(s4[0] + s4[1] + s4[2] + s4[3]);
        }
    } else {
        // ---------------- numerator partials (concurrent blocks) ----------------
        const int nb = blockIdx.x - FWD_BLOCKS;   // 0..63
        const int q  = nb >> 1;
        const int b  = (nb & 1) * 256 + threadIdx.x;
        const int s0 = q * QLEN;

        int tg[QLEN + 1];
        tg[0] = (s0 == 0) ? PAD_I : tags[(s0 - 1)*B_SZ + b];
        #pragma unroll
        for (int k = 0; k < QLEN; ++k)
            tg[k + 1] = tags[(s0 + k)*B_SZ + b];

        float acc = 0.f;
        int cnt = 0;
        if (q == 0) {
            const int t0 = tg[1];
            const int t0w = (t0 < 0) ? t0 + TP2 : t0;
            acc += trans[T_TAGS*TP2 + t0w];
        }
        #pragma unroll
        for (int k = 0; k < QLEN; ++k) {
            const int s = s0 + k;
            const int c = tg[k + 1];
            const float m = (c != PAD_I) ? 1.f : 0.f;
            cnt += (c != PAD_I) ? 1 : 0;
            if (s >= 1) {
                const int p  = tg[k];
                const int pw = (p < 0) ? p + TP2 : p;
                const int cw = (c < 0) ? c + TP2 : c;
                acc += trans[pw*TP2 + cw] * m;
            }
            if (s <= S_LEN - 2) {
                int cc = c; if (cc < 0) cc = 0;
                acc += em[((size_t)s*B_SZ + b)*T_TAGS + cc] * m;
            }
        }
        pl[q*B_SZ + b] = acc;
        pc[q*B_SZ + b] = cnt;
    }
}

// ---------------- finish: last-step terms + mean(llh - denom) ----------------
__global__ __launch_bounds__(512) void finish_kernel(
    const float* __restrict__ em,
    const float* __restrict__ trans,
    const int*   __restrict__ tags,
    const float* __restrict__ pl, const int* __restrict__ pc,
    const float* __restrict__ denom,
    float* __restrict__ out)
{
    const int b = threadIdx.x;
    float llh = 0.f;
    int cnt = 0;
    #pragma unroll
    for (int q = 0; q < NQ; ++q) {
        llh += pl[q*B_SZ + b];
        cnt += pc[q*B_SZ + b];
    }
    int li = cnt - 1; if (li < 0) li = 0;
    const int lt  = tags[li*B_SZ + b];
    const int ltw = (lt < 0) ? lt + TP2 : lt;
    llh += trans[ltw*TP2 + (T_TAGS + 1)];
    const float ml = (tags[(S_LEN - 1)*B_SZ + b] != PAD_I) ? 1.f : 0.f;
    int ltc = lt; if (ltc < 0) ltc = 0;
    llh += em[((size_t)(S_LEN - 1)*B_SZ + b)*T_TAGS + ltc] * ml;

    float v = llh - denom[b];
    #pragma unroll
    for (int off = 32; off; off >>= 1)
        v += __shfl_xor(v, off);
    __shared__ float sred[8];
    if ((b & 63) == 0) sred[b >> 6] = v;
    __syncthreads();
    if (b == 0) {
        float s = 0.f;
        #pragma unroll
        for (int k = 0; k < 8; ++k) s += sred[k];
        out[0] = s * (1.f / (float)B_SZ);
    }
}

extern "C" void kernel_launch(void* const* d_in, const int* in_sizes, int n_in,
                              void* d_out, int out_size, void* d_ws, size_t ws_size,
                              hipStream_t stream) {
    const float* em    = (const float*)d_in[0];
    const float* trans = (const float*)d_in[1];
    const int*   tags  = (const int*)d_in[2];
    float* out   = (float*)d_out;

    float* denom = (float*)d_ws;                 // 512 f
    float* pl    = denom + B_SZ;                 // NQ*512 f
    int*   pc    = (int*)(pl + NQ*B_SZ);         // NQ*512 i

    crf_main<<<TOT_BLOCKS, 256, 0, stream>>>(em, trans, tags, denom, pl, pc);
    finish_kernel<<<1, B_SZ, 0, stream>>>(em, trans, tags, pl, pc, denom, out);
}

// Round 5
// 220.481 us; speedup vs baseline: 1.8003x; 1.8003x over previous
//
#include <hip/hip_runtime.h>

#define S_LEN 256
#define B_SZ  512
#define T_TAGS 128
#define TP2   130
#define PAD_I (-1)
#define RS    4

#define FWD_BLOCKS 32
#define NQ 32
#define QLEN 8
#define NUM_SUB 4
#define NUM_BLOCKS (NQ * NUM_SUB)
#define TOT_BLOCKS (FWD_BLOCKS + NUM_BLOCKS)

typedef __bf16 bf16x8 __attribute__((ext_vector_type(8)));
typedef float  f32x4  __attribute__((ext_vector_type(4)));

// logical k-slot (c,lg,e) -> physical src-tag j. Chosen so D(reg-layout) -> B(frag-layout)
// is same-lane: B slot (c,lg,e) = D[jt=2c+(e>>2)] reg r=(e&3) of the SAME lane.
#define PI_J(c, lg, e) ((2*(c) + ((e) >> 2))*16 + (lg)*4 + ((e) & 3))

// LDS-only barrier: leaves global loads in flight.
__device__ __forceinline__ void bar_lds() {
    asm volatile("s_waitcnt lgkmcnt(0)\n\ts_barrier" ::: "memory");
}

__device__ __forceinline__ void consumer_step(
    int s, int buf,
    const bf16x8 (&A)[8][4], bf16x8 (&Q)[4], float &M, int &tgc,
    const int* __restrict__ tags, int b0, int l, int lm,
    const float (&EE)[2][8][64][4])
{
    const int sn  = (s + 1 < S_LEN) ? s + 1 : S_LEN - 1;
    const int tgn = tags[sn * B_SZ + b0 + lm];          // prefetch next tag

    // D[jt] = E^T x Q : lane l -> (j = jt*16 + (l>>4)*4 + r, b = b0 + (l&15))
    f32x4 d[8];
    const f32x4 z = {0.f, 0.f, 0.f, 0.f};
    #pragma unroll
    for (int jt = 0; jt < 8; ++jt) {
        d[jt] = __builtin_amdgcn_mfma_f32_16x16x32_bf16(A[jt][0], Q[0], z, 0, 0, 0);
        #pragma unroll
        for (int c = 1; c < 4; ++c)
            d[jt] = __builtin_amdgcn_mfma_f32_16x16x32_bf16(A[jt][c], Q[c], d[jt], 0, 0, 0);
    }
    // u = d * exp(em[s])   (EE produced by producer waves)
    float u[8][4];
    #pragma unroll
    for (int jt = 0; jt < 8; ++jt) {
        const f32x4 ee = *(const f32x4*)&EE[buf][jt][l][0];
        #pragma unroll
        for (int r = 0; r < 4; ++r) u[jt][r] = d[jt][r] * ee[r];
    }
    // amortized rescale: every RS steps. invariant: lp = M + log P
    float Mn = M;
    if ((s & (RS - 1)) == 0) {
        float R = u[0][0];
        #pragma unroll
        for (int jt = 0; jt < 8; ++jt)
            #pragma unroll
            for (int r = 0; r < 4; ++r) R = fmaxf(R, u[jt][r]);
        R = fmaxf(R, __shfl_xor(R, 16));
        R = fmaxf(R, __shfl_xor(R, 32));
        const float rr = 1.0f / R;
        Mn = M + __logf(R);
        #pragma unroll
        for (int jt = 0; jt < 8; ++jt)
            #pragma unroll
            for (int r = 0; r < 4; ++r) u[jt][r] *= rr;
    }
    // pack to next B-fragments — same-lane thanks to PI_J permutation
    bf16x8 Qn[4];
    #pragma unroll
    for (int c = 0; c < 4; ++c)
        #pragma unroll
        for (int e = 0; e < 8; ++e)
            Qn[c][e] = (__bf16)u[2*c + (e >> 2)][e & 3];
    const bool live = (tgc != PAD_I);
    M = live ? Mn : M;
    #pragma unroll
    for (int c = 0; c < 4; ++c) Q[c] = live ? Qn[c] : Q[c];
    tgc = tgn;
}

__global__ __launch_bounds__(192) void crf_main(
    const float* __restrict__ em,     // (S,B,T)
    const float* __restrict__ trans,  // (T+2,T+2)
    const int*   __restrict__ tags,   // (S,B)
    float* __restrict__ denom_out,    // (B)
    float* __restrict__ pl,           // (NQ,B)
    int*   __restrict__ pc)           // (NQ,B)
{
    const int t = threadIdx.x;
    if (blockIdx.x < FWD_BLOCKS) {
        const int w  = t >> 6;        // wave role: 0 = consumer, 1/2 = producers
        const int l  = t & 63;
        const int lm = l & 15;
        const int lg = l >> 4;
        const int b0 = blockIdx.x * 16;

        __shared__ __align__(16) float EE[2][8][64][4];   // exp(em) ring, 16 KB

        if (w == 0) {
            // ---- consumer: owns the whole 128x16 state chain ----
            bf16x8 A[8][4];   // E^T fragments, permuted k
            #pragma unroll
            for (int jt = 0; jt < 8; ++jt)
                #pragma unroll
                for (int c = 0; c < 4; ++c)
                    #pragma unroll
                    for (int e = 0; e < 8; ++e)
                        A[jt][c][e] = (__bf16)__expf(trans[PI_J(c, lg, e)*TP2 + jt*16 + lm]);

            // Q init: P_1 = exp(trans[start][j] + em[0][b][j]), M = 0
            f32x4 em0[8];
            #pragma unroll
            for (int jt = 0; jt < 8; ++jt)
                em0[jt] = *(const f32x4*)&em[((size_t)0*B_SZ + b0 + lm)*T_TAGS + jt*16 + lg*4];
            bf16x8 Q[4];
            #pragma unroll
            for (int c = 0; c < 4; ++c)
                #pragma unroll
                for (int e = 0; e < 8; ++e) {
                    const int j  = PI_J(c, lg, e);
                    const int jt = 2*c + (e >> 2);
                    const int r  = e & 3;
                    Q[c][e] = (__bf16)__expf(trans[T_TAGS*TP2 + j] + em0[jt][r]);
                }
            float M = 0.f;
            int tgc = tags[1*B_SZ + b0 + lm];
            bar_lds();                                   // matches producer prologue

            for (int i = 1; i < S_LEN - 1; i += 2) {
                consumer_step(i,     1, A, Q, M, tgc, tags, b0, l, lm, EE);
                bar_lds();
                consumer_step(i + 1, 0, A, Q, M, tgc, tags, b0, l, lm, EE);
                bar_lds();
            }
            consumer_step(S_LEN - 1, 1, A, Q, M, tgc, tags, b0, l, lm, EE);

            // epilogue: denom[b] = M + log(sum_j P[j]*exp(tend[j]))
            float sum = 0.f;
            #pragma unroll
            for (int c = 0; c < 4; ++c)
                #pragma unroll
                for (int e = 0; e < 8; ++e)
                    sum += (float)Q[c][e] * __expf(trans[PI_J(c, lg, e)*TP2 + (T_TAGS + 1)]);
            sum += __shfl_xor(sum, 16);
            sum += __shfl_xor(sum, 32);
            if (l < 16)
                denom_out[b0 + l] = M + __logf(sum);
        } else {
            // ---- producers: EE[(s)&1] = exp(em[s]); ping-pong regs ----
            const int pjt0 = (w - 1) * 4;
            f32x4 pA[4], pB[4];
            #pragma unroll
            for (int q = 0; q < 4; ++q)
                pA[q] = *(const f32x4*)&em[((size_t)1*B_SZ + b0 + lm)*T_TAGS + (pjt0 + q)*16 + lg*4];
            #pragma unroll
            for (int q = 0; q < 4; ++q) {
                f32x4 v;
                #pragma unroll
                for (int r = 0; r < 4; ++r) v[r] = __expf(pA[q][r]);
                *(f32x4*)&EE[1][pjt0 + q][l][0] = v;
            }
            #pragma unroll
            for (int q = 0; q < 4; ++q)
                pB[q] = *(const f32x4*)&em[((size_t)2*B_SZ + b0 + lm)*T_TAGS + (pjt0 + q)*16 + lg*4];
            bar_lds();

            for (int i = 1; i < S_LEN - 1; i += 2) {
                // A-half: EE[0] <- exp(pB)=exp(em[i+1]); load pA <- em[i+2]
                #pragma unroll
                for (int q = 0; q < 4; ++q) {
                    f32x4 v;
                    #pragma unroll
                    for (int r = 0; r < 4; ++r) v[r] = __expf(pB[q][r]);
                    *(f32x4*)&EE[0][pjt0 + q][l][0] = v;
                }
                #pragma unroll
                for (int q = 0; q < 4; ++q)
                    pA[q] = *(const f32x4*)&em[((size_t)(i + 2)*B_SZ + b0 + lm)*T_TAGS + (pjt0 + q)*16 + lg*4];
                bar_lds();
                // B-half: EE[1] <- exp(pA)=exp(em[i+2]); load pB <- em[i+3]
                #pragma unroll
                for (int q = 0; q < 4; ++q) {
                    f32x4 v;
                    #pragma unroll
                    for (int r = 0; r < 4; ++r) v[r] = __expf(pA[q][r]);
                    *(f32x4*)&EE[1][pjt0 + q][l][0] = v;
                }
                const int s3 = (i + 3 < S_LEN) ? i + 3 : S_LEN - 1;
                #pragma unroll
                for (int q = 0; q < 4; ++q)
                    pB[q] = *(const f32x4*)&em[((size_t)s3*B_SZ + b0 + lm)*T_TAGS + (pjt0 + q)*16 + lg*4];
                bar_lds();
            }
            // final consumer step needs no new EE; no more barriers anywhere.
        }
    } else {
        // ---------------- numerator partials ----------------
        if (t >= 128) return;
        const int nb = blockIdx.x - FWD_BLOCKS;   // 0..127
        const int q  = nb >> 2;                   // s-chunk 0..31
        const int b  = (nb & 3) * 128 + t;
        const int s0 = q * QLEN;

        int tg[QLEN + 1];
        tg[0] = (s0 == 0) ? PAD_I : tags[(s0 - 1)*B_SZ + b];
        #pragma unroll
        for (int k = 0; k < QLEN; ++k)
            tg[k + 1] = tags[(s0 + k)*B_SZ + b];

        float acc = 0.f;
        int cnt = 0;
        if (q == 0) {
            const int t0  = tg[1];
            const int t0w = (t0 < 0) ? t0 + TP2 : t0;
            acc += trans[T_TAGS*TP2 + t0w];
        }
        #pragma unroll
        for (int k = 0; k < QLEN; ++k) {
            const int s = s0 + k;
            const int c = tg[k + 1];
            const float m = (c != PAD_I) ? 1.f : 0.f;
            cnt += (c != PAD_I) ? 1 : 0;
            if (s >= 1) {
                const int p  = tg[k];
                const int pw = (p < 0) ? p + TP2 : p;
                const int cw = (c < 0) ? c + TP2 : c;
                acc += trans[pw*TP2 + cw] * m;
            }
            if (s <= S_LEN - 2) {
                int cc = c; if (cc < 0) cc = 0;
                acc += em[((size_t)s*B_SZ + b)*T_TAGS + cc] * m;
            }
        }
        pl[q*B_SZ + b] = acc;
        pc[q*B_SZ + b] = cnt;
    }
}

// ---------------- finish: last-step terms + mean(llh - denom) ----------------
__global__ __launch_bounds__(64) void finish_kernel(
    const float* __restrict__ em,
    const float* __restrict__ trans,
    const int*   __restrict__ tags,
    const float* __restrict__ pl, const int* __restrict__ pc,
    const float* __restrict__ denom,
    float* __restrict__ out)
{
    const int b = blockIdx.x * 64 + threadIdx.x;
    float llh = 0.f;
    int cnt = 0;
    #pragma unroll
    for (int q = 0; q < NQ; ++q) {
        llh += pl[q*B_SZ + b];
        cnt += pc[q*B_SZ + b];
    }
    int li = cnt - 1; if (li < 0) li = 0;
    const int lt  = tags[li*B_SZ + b];
    const int ltw = (lt < 0) ? lt + TP2 : lt;
    llh += trans[ltw*TP2 + (T_TAGS + 1)];
    const float ml = (tags[(S_LEN - 1)*B_SZ + b] != PAD_I) ? 1.f : 0.f;
    int ltc = lt; if (ltc < 0) ltc = 0;
    llh += em[((size_t)(S_LEN - 1)*B_SZ + b)*T_TAGS + ltc] * ml;

    float v = llh - denom[b];
    #pragma unroll
    for (int off = 32; off; off >>= 1)
        v += __shfl_xor(v, off);
    if (threadIdx.x == 0)
        atomicAdd(out, v * (1.f / (float)B_SZ));
}

extern "C" void kernel_launch(void* const* d_in, const int* in_sizes, int n_in,
                              void* d_out, int out_size, void* d_ws, size_t ws_size,
                              hipStream_t stream) {
    const float* em    = (const float*)d_in[0];
    const float* trans = (const float*)d_in[1];
    const int*   tags  = (const int*)d_in[2];
    float* out   = (float*)d_out;

    float* denom = (float*)d_ws;                 // 512 f
    float* pl    = denom + B_SZ;                 // NQ*512 f
    int*   pc    = (int*)(pl + NQ*B_SZ);         // NQ*512 i

    hipMemsetAsync(d_out, 0, sizeof(float), stream);
    crf_main<<<TOT_BLOCKS, 192, 0, stream>>>(em, trans, tags, denom, pl, pc);
    finish_kernel<<<B_SZ / 64, 64, 0, stream>>>(em, trans, tags, pl, pc, denom, out);
}